// Round 5
// baseline (41.420 us; speedup 1.0000x reference)
//
#include <hip/hip_runtime.h>

#define AR 8
#define SEQ 4096
#define BATCH 8192
#define OUTW (AR + SEQ)   // 4104 floats per output row

typedef float f32x4 __attribute__((ext_vector_type(4)));

// ---------------- Phase 1: C[t] = w^T A^t via per-block binary decomposition ----------------
// A = companion matrix (row-vector convention): (R*A)_j = R_{j-1} + R_7 * w_j, i.e.
// A[i][j] = (i==7) ? w_j : (i==j-1).  16 blocks x 256 threads; block b owns t in [256b, 256b+256).
__global__ __launch_bounds__(256) void coeff_kernel(const float* __restrict__ W,
                                                    float* __restrict__ C) {
    __shared__ float P[12][AR][AR];   // P[k] = A^(2^k), 3 KB
    __shared__ float w[AR];
    const int tid = threadIdx.x;

    if (tid < AR) w[tid] = W[tid];
    __syncthreads();

    if (tid < 64) {
        const int i = tid >> 3, j = tid & 7;
        P[0][i][j] = (i == 7) ? w[j] : ((i == j - 1) ? 1.f : 0.f);
    }
    __syncthreads();

    // Cooperative squaring chain: P[k+1] = P[k] * P[k]
    for (int k = 0; k < 11; ++k) {
        if (tid < 64) {
            const int i = tid >> 3, j = tid & 7;
            float v = 0.f;
            #pragma unroll
            for (int q = 0; q < AR; ++q) v += P[k][i][q] * P[k][q][j];
            P[k + 1][i][j] = v;       // distinct array from P[k]: no barrier needed before write
        }
        __syncthreads();              // P[k+1] visible before next round / consumers
    }

    // Per-thread row: r = w^T * prod_{set bits k of t} A^(2^k)
    const int t = blockIdx.x * 256 + tid;
    float r[AR];
    #pragma unroll
    for (int j = 0; j < AR; ++j) r[j] = w[j];
    #pragma unroll
    for (int k = 0; k < 12; ++k) {
        if ((t >> k) & 1) {
            float nr[AR];
            #pragma unroll
            for (int j = 0; j < AR; ++j) {
                float s = 0.f;
                #pragma unroll
                for (int q = 0; q < AR; ++q) s += r[q] * P[k][q][j];
                nr[j] = s;
            }
            #pragma unroll
            for (int j = 0; j < AR; ++j) r[j] = nr[j];
        }
    }

    f32x4* dst = reinterpret_cast<f32x4*>(C);
    dst[(size_t)t * 2 + 0] = (f32x4){r[0], r[1], r[2], r[3]};
    dst[(size_t)t * 2 + 1] = (f32x4){r[4], r[5], r[6], r[7]};
}

// ---------------- Phase 2: out = [y | y @ C^T] ----------------
// Thread: 4 consecutive t (one f32x4/lane, lanes contiguous -> 1KB/wave/store, full 64B lines)
// x 8 batch rows. Nontemporal: write-once 134MB stream, keep it out of L2.
__global__ __launch_bounds__(256) void pred_kernel(const float* __restrict__ y,
                                                   const float* __restrict__ C,
                                                   float* __restrict__ out) {
    const int tt = blockIdx.x * 256 + threadIdx.x;   // float4-group along t: 0..1023
    const int t0 = tt * 4;
    const int row0 = blockIdx.y * 8;

    // 4 C-rows = 32 contiguous floats into registers.
    float c[4][AR];
    const f32x4* Cv = reinterpret_cast<const f32x4*>(C + (size_t)t0 * AR);
    #pragma unroll
    for (int k = 0; k < 4; ++k) {
        f32x4 a = Cv[k * 2 + 0];
        f32x4 b = Cv[k * 2 + 1];
        c[k][0] = a.x; c[k][1] = a.y; c[k][2] = a.z; c[k][3] = a.w;
        c[k][4] = b.x; c[k][5] = b.y; c[k][6] = b.z; c[k][7] = b.w;
    }

    // Hoist all 8 y-rows (wave-uniform addresses -> scalar loads).
    float yy[8][AR];
    #pragma unroll
    for (int r = 0; r < 8; ++r) {
        const f32x4* yv = reinterpret_cast<const f32x4*>(y + (size_t)(row0 + r) * AR);
        f32x4 a = yv[0], b = yv[1];
        yy[r][0] = a.x; yy[r][1] = a.y; yy[r][2] = a.z; yy[r][3] = a.w;
        yy[r][4] = b.x; yy[r][5] = b.y; yy[r][6] = b.z; yy[r][7] = b.w;
    }

    #pragma unroll
    for (int r = 0; r < 8; ++r) {
        float s[4];
        #pragma unroll
        for (int k = 0; k < 4; ++k) {
            float acc = 0.f;
            #pragma unroll
            for (int j = 0; j < AR; ++j) acc += c[k][j] * yy[r][j];
            s[k] = acc;
        }
        f32x4* dst = reinterpret_cast<f32x4*>(out + (size_t)(row0 + r) * OUTW + AR + t0);
        __builtin_nontemporal_store((f32x4){s[0], s[1], s[2], s[3]}, dst);
    }

    // y-head (first 8 output columns) once per row — plain stores (partial lines, let L2 merge).
    if (blockIdx.x == 0 && threadIdx.x < 16) {
        const int r = threadIdx.x >> 1, part = threadIdx.x & 1;
        const int row = row0 + r;
        reinterpret_cast<f32x4*>(out + (size_t)row * OUTW)[part] =
            reinterpret_cast<const f32x4*>(y + (size_t)row * AR)[part];
    }
}

extern "C" void kernel_launch(void* const* d_in, const int* in_sizes, int n_in,
                              void* d_out, int out_size, void* d_ws, size_t ws_size,
                              hipStream_t stream) {
    const float* y = (const float*)d_in[0];
    // d_in[1] = u  -- unused by the reference computation
    const float* W = (const float*)d_in[2];
    float* out = (float*)d_out;
    float* C = (float*)d_ws;                      // 4096*8 floats = 128 KB scratch

    coeff_kernel<<<SEQ / 256, 256, 0, stream>>>(W, C);
    pred_kernel<<<dim3(SEQ / 1024, BATCH / 8), 256, 0, stream>>>(y, C, out);
}

// Round 6
// 31.778 us; speedup vs baseline: 1.3034x; 1.3034x over previous
//
#include <hip/hip_runtime.h>

#define AR 8
#define SEQ 4096
#define BATCH 8192
#define OUTW (AR + SEQ)   // 4104 floats per output row

typedef float f32x4 __attribute__((ext_vector_type(4)));

// ---------------- Phase 1: C[t] = w^T A^t via per-block binary decomposition ----------------
// A = companion matrix (row-vector convention): (R*A)_j = R_{j-1} + R_7 * w_j, i.e.
// A[i][j] = (i==7) ? w_j : (i==j-1).  16 blocks x 256 threads; block b owns t in [256b, 256b+256).
__global__ __launch_bounds__(256) void coeff_kernel(const float* __restrict__ W,
                                                    float* __restrict__ C) {
    __shared__ float P[12][AR][AR];   // P[k] = A^(2^k), 3 KB
    __shared__ float w[AR];
    const int tid = threadIdx.x;

    if (tid < AR) w[tid] = W[tid];
    __syncthreads();

    if (tid < 64) {
        const int i = tid >> 3, j = tid & 7;
        P[0][i][j] = (i == 7) ? w[j] : ((i == j - 1) ? 1.f : 0.f);
    }
    __syncthreads();

    // Cooperative squaring chain: P[k+1] = P[k] * P[k]
    for (int k = 0; k < 11; ++k) {
        if (tid < 64) {
            const int i = tid >> 3, j = tid & 7;
            float v = 0.f;
            #pragma unroll
            for (int q = 0; q < AR; ++q) v += P[k][i][q] * P[k][q][j];
            P[k + 1][i][j] = v;       // distinct array from P[k]: no barrier needed before write
        }
        __syncthreads();              // P[k+1] visible before next round / consumers
    }

    // Per-thread row: r = w^T * prod_{set bits k of t} A^(2^k)
    const int t = blockIdx.x * 256 + tid;
    float r[AR];
    #pragma unroll
    for (int j = 0; j < AR; ++j) r[j] = w[j];
    #pragma unroll
    for (int k = 0; k < 12; ++k) {
        if ((t >> k) & 1) {
            float nr[AR];
            #pragma unroll
            for (int j = 0; j < AR; ++j) {
                float s = 0.f;
                #pragma unroll
                for (int q = 0; q < AR; ++q) s += r[q] * P[k][q][j];
                nr[j] = s;
            }
            #pragma unroll
            for (int j = 0; j < AR; ++j) r[j] = nr[j];
        }
    }

    f32x4* dst = reinterpret_cast<f32x4*>(C);
    dst[(size_t)t * 2 + 0] = (f32x4){r[0], r[1], r[2], r[3]};
    dst[(size_t)t * 2 + 1] = (f32x4){r[4], r[5], r[6], r[7]};
}

// ---------------- Phase 2: out = [y | y @ C^T], grid-stride over row-groups ----------------
// Thread: one f32x4 t-tile (lanes contiguous -> 1KB/wave/store) x 8 batch rows per iter,
// looping 4 row-group iterations with the C tile held in registers. Plain cached stores
// (NT measured 1.78x write amplification at 32B lane stride in R3, and -5us even with
// full lines in R5 -- do not use NT on gfx950 here).
__global__ __launch_bounds__(256) void pred_kernel(const float* __restrict__ y,
                                                   const float* __restrict__ C,
                                                   float* __restrict__ out) {
    const int tt = blockIdx.x * 256 + threadIdx.x;   // float4-group along t: 0..1023
    const int t0 = tt * 4;

    // 4 C-rows = 32 contiguous floats into registers, reused across all row-groups.
    float c[4][AR];
    const f32x4* Cv = reinterpret_cast<const f32x4*>(C + (size_t)t0 * AR);
    #pragma unroll
    for (int k = 0; k < 4; ++k) {
        f32x4 a = Cv[k * 2 + 0];
        f32x4 b = Cv[k * 2 + 1];
        c[k][0] = a.x; c[k][1] = a.y; c[k][2] = a.z; c[k][3] = a.w;
        c[k][4] = b.x; c[k][5] = b.y; c[k][6] = b.z; c[k][7] = b.w;
    }

    for (int rg = blockIdx.y; rg < BATCH / 8; rg += gridDim.y) {
        const int row0 = rg * 8;

        // Hoist all 8 y-rows (block-uniform addresses -> scalar loads).
        float yy[8][AR];
        #pragma unroll
        for (int r = 0; r < 8; ++r) {
            const f32x4* yv = reinterpret_cast<const f32x4*>(y + (size_t)(row0 + r) * AR);
            f32x4 a = yv[0], b = yv[1];
            yy[r][0] = a.x; yy[r][1] = a.y; yy[r][2] = a.z; yy[r][3] = a.w;
            yy[r][4] = b.x; yy[r][5] = b.y; yy[r][6] = b.z; yy[r][7] = b.w;
        }

        #pragma unroll
        for (int r = 0; r < 8; ++r) {
            float s[4];
            #pragma unroll
            for (int k = 0; k < 4; ++k) {
                float acc = 0.f;
                #pragma unroll
                for (int j = 0; j < AR; ++j) acc += c[k][j] * yy[r][j];
                s[k] = acc;
            }
            *reinterpret_cast<f32x4*>(out + (size_t)(row0 + r) * OUTW + AR + t0) =
                (f32x4){s[0], s[1], s[2], s[3]};
        }

        // y-head (first 8 output columns) once per row.
        if (blockIdx.x == 0 && threadIdx.x < 16) {
            const int r = threadIdx.x >> 1, part = threadIdx.x & 1;
            const int row = row0 + r;
            reinterpret_cast<f32x4*>(out + (size_t)row * OUTW)[part] =
                reinterpret_cast<const f32x4*>(y + (size_t)row * AR)[part];
        }
    }
}

extern "C" void kernel_launch(void* const* d_in, const int* in_sizes, int n_in,
                              void* d_out, int out_size, void* d_ws, size_t ws_size,
                              hipStream_t stream) {
    const float* y = (const float*)d_in[0];
    // d_in[1] = u  -- unused by the reference computation
    const float* W = (const float*)d_in[2];
    float* out = (float*)d_out;
    float* C = (float*)d_ws;                      // 4096*8 floats = 128 KB scratch

    coeff_kernel<<<SEQ / 256, 256, 0, stream>>>(W, C);
    pred_kernel<<<dim3(SEQ / 1024, 256), 256, 0, stream>>>(y, C, out);
}

// Round 7
// 27.487 us; speedup vs baseline: 1.5069x; 1.1561x over previous
//
#include <hip/hip_runtime.h>

#define AR 8
#define SEQ 4096
#define BATCH 8192
#define OUTW (AR + SEQ)   // 4104 floats per output row

typedef float f32x4 __attribute__((ext_vector_type(4)));

// ---------------- Fused: out = [y | y @ C^T] with C derived in-block ----------------
// A = companion matrix (row-vector convention): (R*A)_j = R_{j-1} + R_7 * w_j.
// Per block: LDS table P[k] = A^(2^k), k=0..11 (11 cooperative 8x8 squarings).
// Per thread: C-row for t0 = 4*(bx*256+tid) via binary decomposition (bits 2..11),
// then +1,+2,+3 via companion advance. C lives only in registers -- no global C.
// Stores: one f32x4 per lane, lanes contiguous (1KB/wave full-line bursts), cached
// (NT measured 1.78x write amplification at 32B lane stride in R3 and -5us even with
// full lines in R5 -- do not use NT for this on gfx950).
__global__ __launch_bounds__(256, 4) void arx_fused_kernel(const float* __restrict__ y,
                                                           const float* __restrict__ W,
                                                           float* __restrict__ out) {
    __shared__ float P[12][AR][AR];   // P[k] = A^(2^k), 3 KB
    __shared__ float w[AR];
    const int tid = threadIdx.x;

    if (tid < AR) w[tid] = W[tid];
    __syncthreads();

    if (tid < 64) {
        const int i = tid >> 3, j = tid & 7;
        P[0][i][j] = (i == 7) ? w[j] : ((i == j - 1) ? 1.f : 0.f);
    }
    __syncthreads();

    // Cooperative squaring chain: P[k+1] = P[k] * P[k]
    for (int k = 0; k < 11; ++k) {
        if (tid < 64) {
            const int i = tid >> 3, j = tid & 7;
            float v = 0.f;
            #pragma unroll
            for (int q = 0; q < AR; ++q) v += P[k][i][q] * P[k][q][j];
            P[k + 1][i][j] = v;       // distinct array from P[k]
        }
        __syncthreads();
    }

    // Per-thread 4 C-rows in registers.
    const int tt = blockIdx.x * 256 + tid;   // f32x4-group along t: 0..1023
    const int t0 = tt * 4;

    float c[4][AR];
    {
        float r[AR];
        #pragma unroll
        for (int j = 0; j < AR; ++j) r[j] = w[j];          // C[0] = w^T
        #pragma unroll
        for (int k = 2; k < 12; ++k) {                     // t0 has bits >= 2 only
            if ((t0 >> k) & 1) {
                float nr[AR];
                #pragma unroll
                for (int j = 0; j < AR; ++j) {
                    float s = 0.f;
                    #pragma unroll
                    for (int q = 0; q < AR; ++q) s += r[q] * P[k][q][j];
                    nr[j] = s;
                }
                #pragma unroll
                for (int j = 0; j < AR; ++j) r[j] = nr[j];
            }
        }
        #pragma unroll
        for (int j = 0; j < AR; ++j) c[0][j] = r[j];
        #pragma unroll
        for (int k = 1; k < 4; ++k) {                      // companion advances
            const float c7 = c[k - 1][AR - 1];
            c[k][0] = c7 * w[0];
            #pragma unroll
            for (int j = 1; j < AR; ++j) c[k][j] = c[k - 1][j - 1] + c7 * w[j];
        }
    }

    // Grid-stride over row-groups; C tile stays in registers.
    for (int rg = blockIdx.y; rg < BATCH / 8; rg += gridDim.y) {
        const int row0 = rg * 8;

        // Hoist all 8 y-rows (block-uniform addresses -> scalar loads).
        float yy[8][AR];
        #pragma unroll
        for (int r = 0; r < 8; ++r) {
            const f32x4* yv = reinterpret_cast<const f32x4*>(y + (size_t)(row0 + r) * AR);
            f32x4 a = yv[0], b = yv[1];
            yy[r][0] = a.x; yy[r][1] = a.y; yy[r][2] = a.z; yy[r][3] = a.w;
            yy[r][4] = b.x; yy[r][5] = b.y; yy[r][6] = b.z; yy[r][7] = b.w;
        }

        #pragma unroll
        for (int r = 0; r < 8; ++r) {
            float s[4];
            #pragma unroll
            for (int k = 0; k < 4; ++k) {
                float acc = 0.f;
                #pragma unroll
                for (int j = 0; j < AR; ++j) acc += c[k][j] * yy[r][j];
                s[k] = acc;
            }
            *reinterpret_cast<f32x4*>(out + (size_t)(row0 + r) * OUTW + AR + t0) =
                (f32x4){s[0], s[1], s[2], s[3]};
        }

        // y-head (first 8 output columns) once per row.
        if (blockIdx.x == 0 && threadIdx.x < 16) {
            const int r = threadIdx.x >> 1, part = threadIdx.x & 1;
            const int row = row0 + r;
            reinterpret_cast<f32x4*>(out + (size_t)row * OUTW)[part] =
                reinterpret_cast<const f32x4*>(y + (size_t)row * AR)[part];
        }
    }
}

extern "C" void kernel_launch(void* const* d_in, const int* in_sizes, int n_in,
                              void* d_out, int out_size, void* d_ws, size_t ws_size,
                              hipStream_t stream) {
    const float* y = (const float*)d_in[0];
    // d_in[1] = u  -- unused by the reference computation
    const float* W = (const float*)d_in[2];
    float* out = (float*)d_out;

    arx_fused_kernel<<<dim3(SEQ / 1024, 256), 256, 0, stream>>>(y, W, out);
}